// Round 7
// baseline (1763.380 us; speedup 1.0000x reference)
//
#include <hip/hip_runtime.h>

// GRU decoder, bf16 MFMA. R14 = R13 with the nontemporal-builtin type fix
// (HIP float2 is a class type; clang's nontemporal builtin needs a native
// vector -> use ext_vector_type(2) float for the nt feat loads).
//
// R13 rationale: protect the weight set's cache residency.
// R12 post-mortem: kt8/9 LDS staging cut FETCH exactly as predicted
// (4.24->3.82 GB) but moving the kt0/kt1 prefetch inside the t-loop lost
// R8's cross-barrier cover (1562 vs 1503). Structural finding: FETCH 3.82GB
// vs 210 MB compulsory = the 480 KB time-invariant weight set misses
// L2+L3 at ~40% because ~350 MB/dispatch of single-use streams (feat reads,
// write stream) continuously evict it; the resulting HBM burst queuing is
// the latency a depth-2 register pipeline can't hide. Changes:
//  * nontemporal loads for feat, nontemporal stores for out: streaming
//    data no longer evicts the weight set from L2/L3.
//  * cross-barrier prefetch restored (R8's win): next step's kt0/kt1
//    frags issue after the K-loop, BEFORE the S1 barrier.
//  * kt8/9 LDS residency and all other structure from R12 unchanged.

#define Bdim 8192
#define Tdim 96
#define Fdim 64
#define Hdim 256
#define BM   32
#define XS   72    // feat row stride (bf16): 64 + 8 pad
#define HS   264   // h row stride (bf16): 256 + 8 pad

typedef __attribute__((ext_vector_type(8))) short s16x8;
typedef __attribute__((ext_vector_type(4))) float f32x4;
typedef __attribute__((ext_vector_type(2))) float f32x2;

#define MFMA __builtin_amdgcn_mfma_f32_16x16x32_bf16

__device__ __forceinline__ unsigned short f2bf(float f) {
    union { float f; unsigned u; } v; v.f = f;
    unsigned r = v.u + 0x7FFFu + ((v.u >> 16) & 1u);   // RNE
    return (unsigned short)(r >> 16);
}

__device__ __forceinline__ float sigm_fast(float x) {
    return __builtin_amdgcn_rcpf(1.0f + __expf(-x));
}
__device__ __forceinline__ float tanh_fast(float x) {
    return 1.0f - 2.0f * __builtin_amdgcn_rcpf(1.0f + __expf(2.0f * x));
}

// ---- one-time weight conversion + B-fragment swizzle (unchanged) ----
// frag f = ((w*10 + kt)*3 + g)*2 + n2, lane l: 8 bf16 at sW[f*512 + l*8].
// lane holds B[k][n], k = kt*32 + (l>>4)*8 + j, n = g*256 + w*32 + n2*16 + (l&15).
// kt 0..7: B row k = Wr[k]; kt 8..9: B row = Wk[1 + (kt-8)*32 + (l>>4)*8 + j].
__global__ void prep_swz(const float* __restrict__ Wk, const float* __restrict__ Wr,
                         unsigned short* __restrict__ sW) {
    int idx = blockIdx.x * blockDim.x + threadIdx.x;
    if (idx >= 480 * 64) return;
    int lane = idx & 63, f = idx >> 6;
    int n2 = f & 1;
    int g  = (f >> 1) % 3;
    int kt = (f / 6) % 10;
    int w  = f / 60;
    int q = lane >> 4, cc = lane & 15;
    int n = g * 256 + w * 32 + n2 * 16 + cc;
    unsigned short* d = sW + (size_t)idx * 8;
#pragma unroll
    for (int j = 0; j < 8; ++j) {
        float v;
        if (kt < 8) v = Wr[(size_t)(kt * 32 + q * 8 + j) * 768 + n];
        else        v = Wk[(size_t)(1 + (kt - 8) * 32 + q * 8 + j) * 768 + n];
        d[j] = f2bf(v);
    }
}

__launch_bounds__(1024)
__global__ void gru_mfma14(
    const float* __restrict__ feat,       // [B,T,F]
    const float* __restrict__ init_state, // [B,H]
    const float* __restrict__ init_inp,   // [B,1]
    const unsigned short* __restrict__ sW,
    const float* __restrict__ Wk,         // row 0 (prev_out rank-1 term)
    const float* __restrict__ ib, const float* __restrict__ rb,
    const float* __restrict__ dw, const float* __restrict__ db,
    float* __restrict__ out)              // [B,T,1]
{
    __shared__ __align__(16) unsigned short xs[2][BM * XS];      // 9.2 KB
    __shared__ __align__(16) unsigned short hs[2][BM * HS];      // 33.8 KB
    __shared__ __align__(16) unsigned short wlds[16 * 2 * 3 * 512]; // 96 KB
    __shared__ float wpart[2][16][BM];                           // 4 KB

    const int tid  = threadIdx.x;
    const int lane = tid & 63;
    const int wv   = tid >> 6;     // wave 0..15: 16 cols per gate
    const int q    = lane >> 4;
    const int c    = lane & 15;
    const int b0   = blockIdx.x * BM;
    const int col  = wv * 16 + c;  // column within each gate, 0..255

    // per-lane epilogue constants (n2 folded into wv)
    const float bz   = ib[col]       + rb[col];
    const float brr  = ib[256 + col] + rb[256 + col];
    const float bxh  = ib[512 + col];
    const float bhh  = rb[512 + col];
    const float wk0z = Wk[col];
    const float wk0r = Wk[256 + col];
    const float wk0h = Wk[512 + col];
    const float dwv  = dw[col];
    const float dbv  = db[0];

    // init h: fp32 in regs + bf16 in LDS (buffer 0)
    float hreg[2][4];     // [mt][i], single column per lane
#pragma unroll
    for (int mt = 0; mt < 2; ++mt)
#pragma unroll
        for (int i = 0; i < 4; ++i) {
            int row = mt * 16 + q * 4 + i;
            float v = init_state[(size_t)(b0 + row) * Hdim + col];
            hreg[mt][i] = v;
            hs[0][row * HS + col] = f2bf(v);
        }

    // seed wpart[1] so the t=0 finish-phase synthesizes prev_out=init_inp:
    // s = dbv + sum_ww wpart[1][ww][r]  ==  init_inp[b0+r]
    if (tid < 16 * BM) {
        int ww = tid >> 5, r = tid & 31;
        wpart[1][ww][r] = (ww == 0) ? (init_inp[b0 + r] - dbv) : 0.0f;
    }

    // stage feat t=0 (1024 threads: 32 rows x 32 float2), non-temporal
    {
        int r = tid >> 5, fi = tid & 31;
        f32x2 f = __builtin_nontemporal_load(
            (const f32x2*)&feat[((size_t)(b0 + r) * Tdim + 0) * Fdim + fi * 2]);
        ushort2 p; p.x = f2bf(f.x); p.y = f2bf(f.y);
        *(ushort2*)&xs[0][r * XS + fi * 2] = p;
    }

    // frag addr: f = w*60 + (kt*3+g)*2 + n2, elements f*512 + lane*8
    const unsigned short* wp0 =
        sW + ((size_t)(wv >> 1) * 60 + (wv & 1)) * 512 + lane * 8;

    // ---- one-time LDS stage of the kt=8,9 (feat-weight) tiles: 96 KB ----
    {
        unsigned short* wldw = wlds + (size_t)wv * 3072 + lane * 8;
#pragma unroll
        for (int j = 0; j < 2; ++j)
#pragma unroll
            for (int g = 0; g < 3; ++g)
                *(s16x8*)(wldw + (j * 3 + g) * 512) =
                    *(const s16x8*)(wp0 + (size_t)((8 + j) * 3 + g) * 1024);
    }

    // prologue prefetch: kt=0,1 frags for t=0 (cross-barrier pipeline head)
    s16x8 bf[2][3];
#pragma unroll
    for (int g = 0; g < 3; ++g) {
        bf[0][g] = *(const s16x8*)(wp0 + (size_t)(0 * 3 + g) * 1024);
        bf[1][g] = *(const s16x8*)(wp0 + (size_t)(1 * 3 + g) * 1024);
    }

    __syncthreads();

    const unsigned short* wld = wlds + (size_t)wv * 3072 + lane * 8;

    for (int t = 0; t < Tdim; ++t) {
        const unsigned short* hsp = hs[t & 1];
        const unsigned short* xsp = xs[t & 1];

        f32x4 az[2], ar[2], ax[2], ah[2];   // [mt]
#pragma unroll
        for (int mt = 0; mt < 2; ++mt) {
            az[mt] = (f32x4)0.0f; ar[mt] = (f32x4)0.0f;
            ax[mt] = (f32x4)0.0f; ah[mt] = (f32x4)0.0f;
        }

        // ---- staged iterations first (b from LDS, a from xs): latency cover ----
#pragma unroll
        for (int j = 0; j < 2; ++j) {
            s16x8 w0 = *(const s16x8*)(wld + (j * 3 + 0) * 512);
            s16x8 w1 = *(const s16x8*)(wld + (j * 3 + 1) * 512);
            s16x8 w2 = *(const s16x8*)(wld + (j * 3 + 2) * 512);
            s16x8 a0 = *(const s16x8*)&xsp[c * XS + j * 32 + q * 8];
            s16x8 a1 = *(const s16x8*)&xsp[(16 + c) * XS + j * 32 + q * 8];
            az[0] = MFMA(a0, w0, az[0], 0, 0, 0);
            az[1] = MFMA(a1, w0, az[1], 0, 0, 0);
            ar[0] = MFMA(a0, w1, ar[0], 0, 0, 0);
            ar[1] = MFMA(a1, w1, ar[1], 0, 0, 0);
            ax[0] = MFMA(a0, w2, ax[0], 0, 0, 0);
            ax[1] = MFMA(a1, w2, ax[1], 0, 0, 0);
        }

        // ---- global-streamed iterations kt=0..7 (bf pre-issued, dist-2) ----
#pragma unroll
        for (int kt = 0; kt < 8; ++kt) {
            s16x8 w0 = bf[kt & 1][0];
            s16x8 w1 = bf[kt & 1][1];
            s16x8 w2 = bf[kt & 1][2];
            if (kt + 2 < 8) {
#pragma unroll
                for (int g = 0; g < 3; ++g)
                    bf[kt & 1][g] =
                        *(const s16x8*)(wp0 + (size_t)((kt + 2) * 3 + g) * 1024);
            }
            s16x8 a0 = *(const s16x8*)&hsp[c * HS + kt * 32 + q * 8];
            s16x8 a1 = *(const s16x8*)&hsp[(16 + c) * HS + kt * 32 + q * 8];
            az[0] = MFMA(a0, w0, az[0], 0, 0, 0);
            az[1] = MFMA(a1, w0, az[1], 0, 0, 0);
            ar[0] = MFMA(a0, w1, ar[0], 0, 0, 0);
            ar[1] = MFMA(a1, w1, ar[1], 0, 0, 0);
            ah[0] = MFMA(a0, w2, ah[0], 0, 0, 0);
            ah[1] = MFMA(a1, w2, ah[1], 0, 0, 0);
        }

        // cross-barrier prefetch: next step's kt=0,1 frags (time-invariant);
        // ~2 phases of flight hidden under finish+epilogue+barriers.
#pragma unroll
        for (int g = 0; g < 3; ++g) {
            bf[0][g] = *(const s16x8*)(wp0 + (size_t)(0 * 3 + g) * 1024);
            bf[1][g] = *(const s16x8*)(wp0 + (size_t)(1 * 3 + g) * 1024);
        }

        // split feat stage: issue the nt global load now, ds_write after epilogue
        f32x2 fnext;
        int fr = tid >> 5, ffi = tid & 31;
        if (t + 1 < Tdim)
            fnext = __builtin_nontemporal_load(
                (const f32x2*)&feat[((size_t)(b0 + fr) * Tdim + (t + 1)) * Fdim + ffi * 2]);

        __syncthreads();   // S1: all hs/xs reads done; wpart(t-1) complete

        // ---- finish step t-1's dense output; prev_out in 's' ----
        float s;
        {
            int r = lane & 31;
            s = dbv;
            const float (*wp)[BM] = wpart[(t - 1) & 1];
#pragma unroll
            for (int ww = 0; ww < 16; ++ww) s += wp[ww][r];
            if (t > 0 && wv == 0 && lane < 32)
                __builtin_nontemporal_store(s, &out[(size_t)(b0 + r) * Tdim + (t - 1)]);
        }

        // ---- epilogue: gates, h update, fused dense partial reduce ----
        unsigned short* hsn = hs[(t + 1) & 1];
#pragma unroll
        for (int mt = 0; mt < 2; ++mt)
#pragma unroll
            for (int i = 0; i < 4; ++i) {
                float pv = __shfl(s, mt * 16 + q * 4 + i, 64);
                float zz = sigm_fast(az[mt][i] + bz + pv * wk0z);
                float rr = sigm_fast(ar[mt][i] + brr + pv * wk0r);
                float cd = tanh_fast(ax[mt][i] + bxh + pv * wk0h +
                                     rr * (ah[mt][i] + bhh));
                float hn = zz * hreg[mt][i] + (1.0f - zz) * cd;
                hreg[mt][i] = hn;
                hsn[(mt * 16 + q * 4 + i) * HS + col] = f2bf(hn);
                float sp = hn * dwv;
                sp += __shfl_xor(sp, 1, 64);
                sp += __shfl_xor(sp, 2, 64);
                sp += __shfl_xor(sp, 4, 64);
                sp += __shfl_xor(sp, 8, 64);
                if (c == 0) wpart[t & 1][wv][mt * 16 + q * 4 + i] = sp;
            }

        // late half of the feat stage
        if (t + 1 < Tdim) {
            ushort2 p; p.x = f2bf(fnext.x); p.y = f2bf(fnext.y);
            *(ushort2*)&xs[(t + 1) & 1][fr * XS + ffi * 2] = p;
        }
        __syncthreads();   // hs/wpart/xs writes visible for next step
    }

    // final dense output for t=95
    {
        int r = lane & 31;
        float s = dbv;
        const float (*wp)[BM] = wpart[(Tdim - 1) & 1];
#pragma unroll
        for (int ww = 0; ww < 16; ++ww) s += wp[ww][r];
        if (wv == 0 && lane < 32)
            __builtin_nontemporal_store(s, &out[(size_t)(b0 + r) * Tdim + (Tdim - 1)]);
    }
}

extern "C" void kernel_launch(void* const* d_in, const int* in_sizes, int n_in,
                              void* d_out, int out_size, void* d_ws, size_t ws_size,
                              hipStream_t stream) {
    const float* feat       = (const float*)d_in[0];
    const float* init_state = (const float*)d_in[1];
    const float* init_inp   = (const float*)d_in[2];
    const float* Wk         = (const float*)d_in[3];
    const float* Wr         = (const float*)d_in[4];
    const float* ib         = (const float*)d_in[5];
    const float* rb         = (const float*)d_in[6];
    const float* dw         = (const float*)d_in[7];
    const float* db         = (const float*)d_in[8];
    float* out              = (float*)d_out;

    unsigned short* sW = (unsigned short*)d_ws;   // 480 frags * 1 KB = 480 KB

    prep_swz<<<120, 256, 0, stream>>>(Wk, Wr, sW);
    gru_mfma14<<<Bdim / BM, 1024, 0, stream>>>(
        feat, init_state, init_inp, sW, Wk, ib, rb, dw, db, out);
}

// Round 8
// 1681.688 us; speedup vs baseline: 1.0486x; 1.0486x over previous
//
#include <hip/hip_runtime.h>

// GRU decoder, bf16 MFMA. R15: weight stream via per-wave global_load_lds
// ring -- zero staging VGPRs, kill the spill->L2-thrash chain.
// Post-mortem chain: WRITE_SIZE == ~600 B/thread in EVERY config (R7 78MB
// @512thr, R8-R14 152MB @1024thr) = per-thread scratch, written once,
// reloaded per step; 19 MB/XCD scratch footprint thrashes the 4MB L2, so
// the 480KB time-invariant weight set misses at ~40% -> ~4GB HBM fetch ->
// burst-BW/latency bound. R11 proved source-level pressure cuts don't
// stop it: the compiler hoists multi-iteration weight-load windows and
// spills on its own. Fix: weights never touch VGPRs.
//  * per-wave private LDS ring, 2 slots x 3 frags x 1KB, depth-2:
//    at kt read slot[kt&1], then lgkmcnt(0), then issue 3x
//    global_load_lds (16B) for kt+2 into the same slot. No block
//    barriers in the kt-loop (producer == consumer wave).
//  * pacing: s_waitcnt vmcnt(3) + sched_barrier before slot reads
//    (outstanding = kt+1's 3 while kt's 3 must be done).
//  * feat load issued at TOP of t-body: always oldest in vmcnt queue ->
//    counted waits stay conservative-correct; also gains K-loop cover.
//  * all frag register buffers / prefetch deleted; epilogue = R12's.
// LDS: xs 9.2K + hs 33.8K + ring 96K + wpart 4K = 142 KB.

#define Bdim 8192
#define Tdim 96
#define Fdim 64
#define Hdim 256
#define BM   32
#define XS   72    // feat row stride (bf16): 64 + 8 pad
#define HS   264   // h row stride (bf16): 256 + 8 pad

typedef __attribute__((ext_vector_type(8))) short s16x8;
typedef __attribute__((ext_vector_type(4))) float f32x4;

#define MFMA __builtin_amdgcn_mfma_f32_16x16x32_bf16

// global(as1) -> LDS(as3) direct 16B/lane copy; dest is wave-uniform base,
// HW adds lane*16 (m104/m173: do NOT add a per-lane LDS offset).
#define GLL(gp, lp) __builtin_amdgcn_global_load_lds(                      \
    (const __attribute__((address_space(1))) void*)(gp),                   \
    (__attribute__((address_space(3))) void*)(lp), 16, 0, 0)

// s_waitcnt imm encoding (gfx9 lineage): [3:0]=vmcnt lo, [6:4]=expcnt,
// [11:8]=lgkmcnt, [15:14]=vmcnt hi.
#define WAIT_VMCNT3 do { __builtin_amdgcn_s_waitcnt(0x0F73);               \
                         __builtin_amdgcn_sched_barrier(0); } while (0)
#define WAIT_LGKM0  do { __builtin_amdgcn_s_waitcnt(0xC07F);               \
                         __builtin_amdgcn_sched_barrier(0); } while (0)

__device__ __forceinline__ unsigned short f2bf(float f) {
    union { float f; unsigned u; } v; v.f = f;
    unsigned r = v.u + 0x7FFFu + ((v.u >> 16) & 1u);   // RNE
    return (unsigned short)(r >> 16);
}

__device__ __forceinline__ float sigm_fast(float x) {
    return __builtin_amdgcn_rcpf(1.0f + __expf(-x));
}
__device__ __forceinline__ float tanh_fast(float x) {
    return 1.0f - 2.0f * __builtin_amdgcn_rcpf(1.0f + __expf(2.0f * x));
}

// ---- one-time weight conversion + B-fragment swizzle (unchanged) ----
// frag f = ((w*10 + kt)*3 + g)*2 + n2, lane l: 8 bf16 at sW[f*512 + l*8].
// lane holds B[k][n], k = kt*32 + (l>>4)*8 + j, n = g*256 + w*32 + n2*16 + (l&15).
// kt 0..7: B row k = Wr[k]; kt 8..9: B row = Wk[1 + (kt-8)*32 + (l>>4)*8 + j].
__global__ void prep_swz(const float* __restrict__ Wk, const float* __restrict__ Wr,
                         unsigned short* __restrict__ sW) {
    int idx = blockIdx.x * blockDim.x + threadIdx.x;
    if (idx >= 480 * 64) return;
    int lane = idx & 63, f = idx >> 6;
    int n2 = f & 1;
    int g  = (f >> 1) % 3;
    int kt = (f / 6) % 10;
    int w  = f / 60;
    int q = lane >> 4, cc = lane & 15;
    int n = g * 256 + w * 32 + n2 * 16 + cc;
    unsigned short* d = sW + (size_t)idx * 8;
#pragma unroll
    for (int j = 0; j < 8; ++j) {
        float v;
        if (kt < 8) v = Wr[(size_t)(kt * 32 + q * 8 + j) * 768 + n];
        else        v = Wk[(size_t)(1 + (kt - 8) * 32 + q * 8 + j) * 768 + n];
        d[j] = f2bf(v);
    }
}

__launch_bounds__(1024)
__global__ void gru_mfma15(
    const float* __restrict__ feat,       // [B,T,F]
    const float* __restrict__ init_state, // [B,H]
    const float* __restrict__ init_inp,   // [B,1]
    const unsigned short* __restrict__ sW,
    const float* __restrict__ Wk,         // row 0 (prev_out rank-1 term)
    const float* __restrict__ ib, const float* __restrict__ rb,
    const float* __restrict__ dw, const float* __restrict__ db,
    float* __restrict__ out)              // [B,T,1]
{
    __shared__ __align__(16) unsigned short xs[2][BM * XS];          // 9.2 KB
    __shared__ __align__(16) unsigned short hs[2][BM * HS];          // 33.8 KB
    __shared__ __align__(16) unsigned short wring[16 * 2 * 3 * 512]; // 96 KB
    __shared__ float wpart[2][16][BM];                               // 4 KB

    const int tid  = threadIdx.x;
    const int lane = tid & 63;
    const int wv   = tid >> 6;     // wave 0..15: 16 cols per gate
    const int q    = lane >> 4;
    const int c    = lane & 15;
    const int b0   = blockIdx.x * BM;
    const int col  = wv * 16 + c;  // column within each gate, 0..255

    // per-lane epilogue constants (n2 folded into wv)
    const float bz   = ib[col]       + rb[col];
    const float brr  = ib[256 + col] + rb[256 + col];
    const float bxh  = ib[512 + col];
    const float bhh  = rb[512 + col];
    const float wk0z = Wk[col];
    const float wk0r = Wk[256 + col];
    const float wk0h = Wk[512 + col];
    const float dwv  = dw[col];
    const float dbv  = db[0];

    // init h: fp32 in regs + bf16 in LDS (buffer 0)
    float hreg[2][4];     // [mt][i], single column per lane
#pragma unroll
    for (int mt = 0; mt < 2; ++mt)
#pragma unroll
        for (int i = 0; i < 4; ++i) {
            int row = mt * 16 + q * 4 + i;
            float v = init_state[(size_t)(b0 + row) * Hdim + col];
            hreg[mt][i] = v;
            hs[0][row * HS + col] = f2bf(v);
        }

    // seed wpart[1] so the t=0 finish-phase synthesizes prev_out=init_inp
    if (tid < 16 * BM) {
        int ww = tid >> 5, r = tid & 31;
        wpart[1][ww][r] = (ww == 0) ? (init_inp[b0 + r] - dbv) : 0.0f;
    }

    // stage feat t=0 (1024 threads: 32 rows x 32 float2)
    {
        int r = tid >> 5, fi = tid & 31;
        float2 f = *(const float2*)&feat[((size_t)(b0 + r) * Tdim + 0) * Fdim + fi * 2];
        ushort2 p; p.x = f2bf(f.x); p.y = f2bf(f.y);
        *(ushort2*)&xs[0][r * XS + fi * 2] = p;
    }

    // per-lane global frag base (lane*16B mirrors GLL's implicit dest stride)
    const unsigned short* wp0 =
        sW + ((size_t)(wv >> 1) * 60 + (wv & 1)) * 512 + lane * 8;
    // per-wave ring base (shorts); slot s frag g at + s*1536 + g*512
    const int rbase = wv * 3072;

    // prologue: stage kt=0 -> slot0, kt=1 -> slot1 (drained by the barrier)
#pragma unroll
    for (int k0 = 0; k0 < 2; ++k0)
#pragma unroll
        for (int g = 0; g < 3; ++g)
            GLL(wp0 + (size_t)(k0 * 3 + g) * 1024,
                &wring[rbase + k0 * 1536 + g * 512]);

    __syncthreads();

    for (int t = 0; t < Tdim; ++t) {
        const unsigned short* hsp = hs[t & 1];
        const unsigned short* xsp = xs[t & 1];

        // feat t+1 issued FIRST: oldest in vmcnt queue (count-safety) and
        // gets the whole K-loop as latency cover. Written to xs post-S1.
        float2 fnext;
        int fr = tid >> 5, ffi = tid & 31;
        if (t + 1 < Tdim)
            fnext = *(const float2*)&feat[((size_t)(b0 + fr) * Tdim + (t + 1)) * Fdim + ffi * 2];

        f32x4 az[2], ar[2], ax[2], ah[2];   // [mt]
#pragma unroll
        for (int mt = 0; mt < 2; ++mt) {
            az[mt] = (f32x4)0.0f; ar[mt] = (f32x4)0.0f;
            ax[mt] = (f32x4)0.0f; ah[mt] = (f32x4)0.0f;
        }

        // ---- K-loop: b-frags from LDS ring, depth-2 gll pipeline ----
#pragma unroll
        for (int kt = 0; kt < 10; ++kt) {
            const int slot = kt & 1;
            WAIT_VMCNT3;   // this kt's 3 frags have landed in LDS

            const unsigned short* bs = &wring[rbase + slot * 1536 + lane * 8];
            s16x8 w0 = *(const s16x8*)(bs + 0 * 512);
            s16x8 w1 = *(const s16x8*)(bs + 1 * 512);
            s16x8 w2 = *(const s16x8*)(bs + 2 * 512);
            s16x8 a0, a1;
            if (kt < 8) {
                a0 = *(const s16x8*)&hsp[c * HS + kt * 32 + q * 8];
                a1 = *(const s16x8*)&hsp[(16 + c) * HS + kt * 32 + q * 8];
            } else {
                a0 = *(const s16x8*)&xsp[c * XS + (kt - 8) * 32 + q * 8];
                a1 = *(const s16x8*)&xsp[(16 + c) * XS + (kt - 8) * 32 + q * 8];
            }

            WAIT_LGKM0;    // slot reads retired -> safe to overwrite
            {
                const int ktn = (kt + 2) % 10;   // wraps into next step's kt0/1
#pragma unroll
                for (int g = 0; g < 3; ++g)
                    GLL(wp0 + (size_t)(ktn * 3 + g) * 1024,
                        &wring[rbase + slot * 1536 + g * 512]);
            }

            az[0] = MFMA(a0, w0, az[0], 0, 0, 0);
            az[1] = MFMA(a1, w0, az[1], 0, 0, 0);
            ar[0] = MFMA(a0, w1, ar[0], 0, 0, 0);
            ar[1] = MFMA(a1, w1, ar[1], 0, 0, 0);
            if (kt < 8) {   // hh terms
                ah[0] = MFMA(a0, w2, ah[0], 0, 0, 0);
                ah[1] = MFMA(a1, w2, ah[1], 0, 0, 0);
            } else {        // xh terms
                ax[0] = MFMA(a0, w2, ax[0], 0, 0, 0);
                ax[1] = MFMA(a1, w2, ax[1], 0, 0, 0);
            }
        }

        __syncthreads();   // S1: hs/xs reads done; wpart(t-1) complete
                           // (also drains in-flight glls for next step)

        // ---- finish step t-1's dense output; prev_out in 's' ----
        float s;
        {
            int r = lane & 31;
            s = dbv;
            const float (*wp)[BM] = wpart[(t - 1) & 1];
#pragma unroll
            for (int ww = 0; ww < 16; ++ww) s += wp[ww][r];
            if (t > 0 && wv == 0 && lane < 32)
                out[(size_t)(b0 + r) * Tdim + (t - 1)] = s;
        }

        // ---- epilogue: gates, h update, fused dense partial reduce ----
        unsigned short* hsn = hs[(t + 1) & 1];
#pragma unroll
        for (int mt = 0; mt < 2; ++mt)
#pragma unroll
            for (int i = 0; i < 4; ++i) {
                float pv = __shfl(s, mt * 16 + q * 4 + i, 64);
                float zz = sigm_fast(az[mt][i] + bz + pv * wk0z);
                float rr = sigm_fast(ar[mt][i] + brr + pv * wk0r);
                float cd = tanh_fast(ax[mt][i] + bxh + pv * wk0h +
                                     rr * (ah[mt][i] + bhh));
                float hn = zz * hreg[mt][i] + (1.0f - zz) * cd;
                hreg[mt][i] = hn;
                hsn[(mt * 16 + q * 4 + i) * HS + col] = f2bf(hn);
                float sp = hn * dwv;
                sp += __shfl_xor(sp, 1, 64);
                sp += __shfl_xor(sp, 2, 64);
                sp += __shfl_xor(sp, 4, 64);
                sp += __shfl_xor(sp, 8, 64);
                if (c == 0) wpart[t & 1][wv][mt * 16 + q * 4 + i] = sp;
            }

        // late half of the feat stage
        if (t + 1 < Tdim) {
            ushort2 p; p.x = f2bf(fnext.x); p.y = f2bf(fnext.y);
            *(ushort2*)&xs[(t + 1) & 1][fr * XS + ffi * 2] = p;
        }
        __syncthreads();   // S2: hs/wpart/xs writes visible for next step
    }

    // final dense output for t=95
    {
        int r = lane & 31;
        float s = dbv;
        const float (*wp)[BM] = wpart[(Tdim - 1) & 1];
#pragma unroll
        for (int ww = 0; ww < 16; ++ww) s += wp[ww][r];
        if (wv == 0 && lane < 32)
            out[(size_t)(b0 + r) * Tdim + (Tdim - 1)] = s;
    }
}

extern "C" void kernel_launch(void* const* d_in, const int* in_sizes, int n_in,
                              void* d_out, int out_size, void* d_ws, size_t ws_size,
                              hipStream_t stream) {
    const float* feat       = (const float*)d_in[0];
    const float* init_state = (const float*)d_in[1];
    const float* init_inp   = (const float*)d_in[2];
    const float* Wk         = (const float*)d_in[3];
    const float* Wr         = (const float*)d_in[4];
    const float* ib         = (const float*)d_in[5];
    const float* rb         = (const float*)d_in[6];
    const float* dw         = (const float*)d_in[7];
    const float* db         = (const float*)d_in[8];
    float* out              = (float*)d_out;

    unsigned short* sW = (unsigned short*)d_ws;   // 480 frags * 1 KB = 480 KB

    prep_swz<<<120, 256, 0, stream>>>(Wk, Wr, sW);
    gru_mfma15<<<Bdim / BM, 1024, 0, stream>>>(
        feat, init_state, init_inp, sW, Wk, ib, rb, dw, db, out);
}